// Round 3
// baseline (348.335 us; speedup 1.0000x reference)
//
#include <hip/hip_runtime.h>

#define T  512
#define B  512
#define NT 64

typedef float v2f __attribute__((ext_vector_type(2)));

__device__ __forceinline__ float rfl(float x) {
    return __uint_as_float(__builtin_amdgcn_readfirstlane(__float_as_uint(x)));
}

// ---------------------------------------------------------------------------
// Fused CRF kernel. 1024 single-wave blocks:
//   blocks [0,512):   denominator (forward algorithm), one chain per block
//   blocks [512,1024): numerator (gather-sum + end transitions via ballot)
//
// Denominator chain design (lane j = tag j):
//   q_j tracks exp(score_j - S); per step
//     p_j = sum_i q_i * E[i][j]          (E = exp(trans), col j in VGPRs, pk_fma)
//     q'_j = p_j * rcp(P) * X_t          (P = readfirstlane(p), X = exp(e - ef))
//     S   += log(P) + ef                 (off critical path)
//   Mask column preloaded to LDS: NO scalar-memory (SMEM) ops inside the loop,
//   so lgkmcnt waits stay precise for the in-order DS pipe (SMEM completes
//   out-of-order vs DS and forces lgkmcnt(0) drains -> the R2 1127-cyc/step
//   stall). Emissions ride a 4-deep register pipeline on the in-order vmcnt
//   path. Single-wave block: no __syncthreads anywhere in the loop.
// ---------------------------------------------------------------------------
__global__ __launch_bounds__(64) void crf_fused(
    const float* __restrict__ emissions,  // [T, B, NT]
    const int*   __restrict__ tags,       // [T, B]
    const int*   __restrict__ mask,       // [T, B]
    const float* __restrict__ startT,     // [NT]
    const float* __restrict__ endT,       // [NT]
    const float* __restrict__ trans,      // [NT, NT]
    float* __restrict__ out)
{
    const int j = threadIdx.x;

    __shared__ __align__(16) float qs[NT];
    __shared__ int mk[T];

    if (blockIdx.x < B) {
        // ================= denominator chain, b = blockIdx.x =================
        const int b = blockIdx.x;

        // stage mask column into LDS (off the serial path; same-wave DS
        // in-order => later reads see these writes, no barrier needed)
#pragma unroll
        for (int m = 0; m < T / 64; ++m)
            mk[j + 64 * m] = mask[(j + 64 * m) * B + b];

        // E column j as float2 pairs over i (v_pk_fma_f32)
        v2f Ep[NT / 2];
#pragma unroll
        for (int m = 0; m < NT / 2; ++m) {
            Ep[m].x = __expf(trans[(2 * m)     * NT + j]);
            Ep[m].y = __expf(trans[(2 * m + 1) * NT + j]);
        }

        const float* pe = emissions + (size_t)b * NT + j;  // step stride B*NT

        const float score0 = startT[j] + pe[0];
        float S = rfl(score0);
        float q = __expf(score0 - S);
        qs[j] = q;

        // emission pipeline: holds e(t+1..t+4) at start of step t
        float e1 = pe[(size_t)1 * B * NT];
        float e2 = pe[(size_t)2 * B * NT];
        float e3 = pe[(size_t)3 * B * NT];
        float e4 = pe[(size_t)4 * B * NT];
        float e5 = pe[(size_t)5 * B * NT];

        float ef = rfl(e1);
        float X  = __expf(e1 - ef);   // X for t=1
        e1 = e2; e2 = e3; e3 = e4; e4 = e5;

#pragma unroll 4
        for (int t = 1; t < T; ++t) {
            const int tn = (t + 5 < T) ? (t + 5) : (T - 1);
            const float eN = pe[(size_t)tn * B * NT];
            const int   mc = mk[t];          // broadcast DS read, lands by tail

            // matvec: p_j = sum_i q_i * E[i][j]
            const float4* q4 = (const float4*)qs;
            v2f a0 = {0.f, 0.f}, a1 = {0.f, 0.f}, a2 = {0.f, 0.f}, a3 = {0.f, 0.f};
#pragma unroll
            for (int k = 0; k < NT / 4; k += 2) {
                const float4 u = q4[k];
                const float4 w = q4[k + 1];
                a0 = __builtin_elementwise_fma((v2f){u.x, u.y}, Ep[2 * k],     a0);
                a1 = __builtin_elementwise_fma((v2f){u.z, u.w}, Ep[2 * k + 1], a1);
                a2 = __builtin_elementwise_fma((v2f){w.x, w.y}, Ep[2 * k + 2], a2);
                a3 = __builtin_elementwise_fma((v2f){w.z, w.w}, Ep[2 * k + 3], a3);
            }
            const v2f s01 = a0 + a1;
            const v2f s23 = a2 + a3;
            const v2f ss  = s01 + s23;
            const float p = ss.x + ss.y;

            // next step's X (independent — fills the LDS-latency bubbles)
            const float efn = rfl(e1);
            const float Xn  = __expf(e1 - efn);

            // tail: renormalize via rcp; select by mask
            const float P  = rfl(p);
            const float qn = p * __builtin_amdgcn_rcpf(P) * X;
            q = mc ? qn : q;
            qs[j] = q;
            S = mc ? (S + __logf(P) + ef) : S;   // scalar side, lags freely

            X = Xn; ef = efn;
            e1 = e2; e2 = e3; e3 = e4; e4 = eN;
        }

        // denominator_b = S + log( sum_j q_j * exp(endT_j) )
        float v = q * __expf(endT[j]);
#pragma unroll
        for (int off = 32; off > 0; off >>= 1)
            v += __shfl_xor(v, off);
        if (j == 0)
            atomicAdd(out, -(S + __logf(v)));    // llh = num - den

    } else {
        // ================= numerator wave, b = blockIdx.x - B ================
        const int b = blockIdx.x - B;

        float acc = 0.f;
        int   cnt = 0;
#pragma unroll
        for (int m = 0; m < T / 64; ++m) {
            const int t  = j + 64 * m;
            const int mv = mask[t * B + b];
            const int tg = tags[t * B + b];
            cnt += (int)__popcll(__ballot(mv != 0));   // wave-uniform count
            if (t == 0) {
                acc += startT[tg] + emissions[(size_t)b * NT + tg];
            } else if (mv) {
                const int tp = tags[(t - 1) * B + b];
                acc += trans[tp * NT + tg]
                     + emissions[(size_t)(t * B + b) * NT + tg];
            }
        }
#pragma unroll
        for (int off = 32; off > 0; off >>= 1)
            acc += __shfl_xor(acc, off);
        if (j == 0) {
            const int last = tags[(size_t)(cnt - 1) * B + b];  // seq_end gather
            atomicAdd(out, acc + endT[last]);
        }
    }
}

extern "C" void kernel_launch(void* const* d_in, const int* in_sizes, int n_in,
                              void* d_out, int out_size, void* d_ws, size_t ws_size,
                              hipStream_t stream) {
    const float* emissions = (const float*)d_in[0];
    const int*   tags      = (const int*)  d_in[1];
    const int*   mask      = (const int*)  d_in[2];
    const float* startT    = (const float*)d_in[3];
    const float* endT      = (const float*)d_in[4];
    const float* trans     = (const float*)d_in[5];
    float* out = (float*)d_out;

    hipMemsetAsync(out, 0, sizeof(float), stream);
    crf_fused<<<2 * B, 64, 0, stream>>>(
        emissions, tags, mask, startT, endT, trans, out);
}

// Round 4
// 222.979 us; speedup vs baseline: 1.5622x; 1.5622x over previous
//
#include <hip/hip_runtime.h>

#define T   512
#define B   512
#define NT  64
#define CH  64            // time-steps per LDS chunk
#define NCH (T / CH)      // 8

typedef float v2f __attribute__((ext_vector_type(2)));

__device__ __forceinline__ float rfl(float x) {
    return __uint_as_float(__builtin_amdgcn_readfirstlane(__float_as_uint(x)));
}

// ---------------------------------------------------------------------------
// Fused CRF. 1024 single-wave blocks: [0,512) denominator chains, [512,1024)
// numerator gather waves.
//
// Denominator (lane j = tag j), per step:
//   p_j = sum_i q_i E[i][j]     (E=exp(trans) col j in VGPRs, v_pk_fma_f32,
//                                q broadcast via 16x ds_read_b128)
//   q'_j = p_j * r * X_j        r = rcp(P_lag)  [lagged normalizer: EXACT,
//                                since S absorbs log(1/r_used); rcp/log/
//                                readfirstlane run in the next step's shadow]
//   S   += log(P_lag) + ef      (cndmask by mask bit)
//
// NOTHING in the step loop touches global memory:
//   - emissions: 64-step chunks staged into double-buffered LDS; the global
//     loads for chunk c+1 are issued at the top of chunk c (~64 steps of
//     slack >> 900-cyc HBM latency), ds_written at the boundary.
//   - mask: per-chunk __ballot -> uint64 in SGPRs, prefetched a chunk ahead.
// So no vmcnt wait can land on the serial chain (the R2/R3 ~900-cyc stall).
// Single-wave blocks; same-wave DS ops are in-order -> no barriers needed.
// ---------------------------------------------------------------------------
__global__ __launch_bounds__(64) void crf_fused(
    const float* __restrict__ emissions,  // [T, B, NT]
    const int*   __restrict__ tags,       // [T, B]
    const int*   __restrict__ mask,       // [T, B]
    const float* __restrict__ startT,     // [NT]
    const float* __restrict__ endT,       // [NT]
    const float* __restrict__ trans,      // [NT, NT]
    float* __restrict__ out)
{
    const int j = threadIdx.x;

    __shared__ __align__(16) float qs[NT];
    __shared__ __align__(16) float ebuf[2][CH][NT];

    if (blockIdx.x < B) {
        // ===================== denominator chain, b = blockIdx.x ============
        const int b = blockIdx.x;

        // E column j as float2 pairs over i (v_pk_fma_f32)
        v2f Ep[NT / 2];
#pragma unroll
        for (int m = 0; m < NT / 2; ++m) {
            Ep[m].x = __expf(trans[(2 * m)     * NT + j]);
            Ep[m].y = __expf(trans[(2 * m + 1) * NT + j]);
        }

        // staging lane mapping: reg k covers steps 4k..4k+3 of a chunk;
        // lane j handles step-subindex j>>4, cols (j&15)*4 .. +3
        const int lr = j >> 4;
        const int lc = (j & 15) * 4;
        const float* src_base = emissions + ((size_t)lr * B + b) * NT + lc;

        float4 stg[16];
        // stage chunk 0 synchronously
#pragma unroll
        for (int k = 0; k < 16; ++k)
            stg[k] = *(const float4*)(src_base + (size_t)(4 * k) * B * NT);
#pragma unroll
        for (int k = 0; k < 16; ++k)
            *(float4*)&ebuf[0][4 * k + lr][lc] = stg[k];
        // issue loads for chunk 1 (consumed a whole chunk later)
#pragma unroll
        for (int k = 0; k < 16; ++k)
            stg[k] = *(const float4*)(src_base + (size_t)(CH + 4 * k) * B * NT);

        // mask pipeline: per-lane value for chunk 0 (ballot'd at chunk top)
        int mpre = mask[j * B + b];

        // t = 0 init
        const float e0  = ebuf[0][0][j];
        const float sc0 = startT[j] + e0;
        float S = rfl(sc0);
        float q = __expf(sc0 - S);
        qs[j] = q;
        float r = 1.0f, lp = 0.0f;   // lagged normalizer (P=1 seed: exact)

        for (int c = 0; c < NCH; ++c) {
            const unsigned long long mbc = __ballot(mpre != 0);
            if (c + 1 < NCH)
                mpre = mask[((c + 1) * CH + j) * B + b];

            if (c > 0) {
                // staged regs were loaded one chunk ago -> long since landed
#pragma unroll
                for (int k = 0; k < 16; ++k)
                    *(float4*)&ebuf[c & 1][4 * k + lr][lc] = stg[k];
                if (c + 1 < NCH) {
#pragma unroll
                    for (int k = 0; k < 16; ++k)
                        stg[k] = *(const float4*)(src_base +
                                  (size_t)((c + 1) * CH + 4 * k) * B * NT);
                }
            }

            const float* eb  = &ebuf[c & 1][0][0];
            const int    tt0 = (c == 0) ? 1 : 0;
#pragma unroll 4
            for (int tt = tt0; tt < CH; ++tt) {
                const float e = eb[tt * NT + j];   // LDS, stride-1: conflict-free

                const float4* q4 = (const float4*)qs;
                v2f a0 = {0.f,0.f}, a1 = {0.f,0.f}, a2 = {0.f,0.f}, a3 = {0.f,0.f};
#pragma unroll
                for (int k = 0; k < NT / 4; k += 2) {
                    const float4 u = q4[k];
                    const float4 w = q4[k + 1];
                    a0 = __builtin_elementwise_fma((v2f){u.x, u.y}, Ep[2 * k],     a0);
                    a1 = __builtin_elementwise_fma((v2f){u.z, u.w}, Ep[2 * k + 1], a1);
                    a2 = __builtin_elementwise_fma((v2f){w.x, w.y}, Ep[2 * k + 2], a2);
                    a3 = __builtin_elementwise_fma((v2f){w.z, w.w}, Ep[2 * k + 3], a3);
                }
                const v2f ss = (a0 + a1) + (a2 + a3);
                const float p = ss.x + ss.y;

                // computed in the matvec's LDS shadow
                const float ef = rfl(e);
                const float X  = __expf(e - ef);

                // tail: two muls + select + write (r, lp are from last step)
                const float qn = p * r * X;
                const bool  mc = (mbc >> tt) & 1ull;
                q = mc ? qn : q;
                qs[j] = q;
                S = mc ? (S + lp + ef) : S;

                // lagged normalizer for NEXT step (off critical path)
                const float P = rfl(p);
                r  = __builtin_amdgcn_rcpf(P);
                lp = __logf(P);
            }
        }

        // denominator_b = S + log( sum_j q_j * exp(endT_j) )
        float v = q * __expf(endT[j]);
#pragma unroll
        for (int off = 32; off > 0; off >>= 1)
            v += __shfl_xor(v, off);
        if (j == 0)
            atomicAdd(out, -(S + __logf(v)));    // llh = num - den

    } else {
        // ===================== numerator wave, b = blockIdx.x - B ===========
        const int b = blockIdx.x - B;

        float acc = 0.f;
        int   cnt = 0;
#pragma unroll
        for (int m = 0; m < T / 64; ++m) {
            const int t  = j + 64 * m;
            const int mv = mask[t * B + b];
            const int tg = tags[t * B + b];
            cnt += (int)__popcll(__ballot(mv != 0));
            if (t == 0) {
                acc += startT[tg] + emissions[(size_t)b * NT + tg];
            } else if (mv) {
                const int tp = tags[(t - 1) * B + b];
                acc += trans[tp * NT + tg]
                     + emissions[(size_t)(t * B + b) * NT + tg];
            }
        }
#pragma unroll
        for (int off = 32; off > 0; off >>= 1)
            acc += __shfl_xor(acc, off);
        if (j == 0) {
            const int last = tags[(size_t)(cnt - 1) * B + b];
            atomicAdd(out, acc + endT[last]);
        }
    }
}

extern "C" void kernel_launch(void* const* d_in, const int* in_sizes, int n_in,
                              void* d_out, int out_size, void* d_ws, size_t ws_size,
                              hipStream_t stream) {
    const float* emissions = (const float*)d_in[0];
    const int*   tags      = (const int*)  d_in[1];
    const int*   mask      = (const int*)  d_in[2];
    const float* startT    = (const float*)d_in[3];
    const float* endT      = (const float*)d_in[4];
    const float* trans     = (const float*)d_in[5];
    float* out = (float*)d_out;

    hipMemsetAsync(out, 0, sizeof(float), stream);
    crf_fused<<<2 * B, 64, 0, stream>>>(
        emissions, tags, mask, startT, endT, trans, out);
}